// Round 14
// baseline (95.896 us; speedup 1.0000x reference)
//
#include <hip/hip_runtime.h>
#include <hip/hip_bf16.h>

#define NUM_TYPES 26
#define NPT 128
#define DIMS 256
#define K_TOTAL 3328
#define N_TOK 8192
#define INV_TEMP (1.0f/0.07f)
#define TM 16
#define MAX_TILES 32
#define NHIST 32

typedef unsigned short ushort_t;
typedef short bf16x8 __attribute__((ext_vector_type(8)));
typedef float f32x4 __attribute__((ext_vector_type(4)));

__device__ __forceinline__ float wave_reduce_sum(float v){
#pragma unroll
  for (int off = 32; off; off >>= 1) v += __shfl_xor(v, off);
  return v;
}

__device__ __forceinline__ unsigned short f2bf(float f){
  __hip_bfloat16 h = __float2bfloat16(f);
  return __builtin_bit_cast(unsigned short, h);
}

#define GLOAD_LDS16(g, s) \
  __builtin_amdgcn_global_load_lds((__attribute__((address_space(1))) void*)(g), \
                                   (__attribute__((address_space(3))) void*)(s), 16, 0, 0)

#define VMWAIT(N) do{ asm volatile("s_waitcnt vmcnt(" #N ")" ::: "memory"); \
                      __builtin_amdgcn_sched_barrier(0); }while(0)

// ---------------- prepk -----------------------------------------------------
// blocks 0..831    : normalize E rows -> Enb (bf16)
// blocks 832..935  : pack EC[tp][ck] (bf16, phase-C tile order, 16KB each)
// blocks 936..1143 : pack EA2[tp][sec*8+kt][code][8] (f32, PLAIN layout)
// blocks 1144..1175: histogram chunks
__global__ __launch_bounds__(256) void prepk(const float* __restrict__ E,
                                             const int* __restrict__ Q,
                                             ushort_t* __restrict__ Enb,
                                             float* __restrict__ EA2,
                                             ushort_t* __restrict__ EC,
                                             int* __restrict__ bh){
  const int t = threadIdx.x;
  const int b = blockIdx.x;
  if (b < 832){
    const int w = t >> 6, l = t & 63;
    const int row = b * 4 + w;
    float4 v = reinterpret_cast<const float4*>(E + (size_t)row * DIMS)[l];
    float ss = v.x*v.x + v.y*v.y + v.z*v.z + v.w*v.w;
    ss = wave_reduce_sum(ss);
    const float inv = 1.0f / sqrtf(ss);
    ushort4 o;
    o.x = f2bf(v.x * inv); o.y = f2bf(v.y * inv);
    o.z = f2bf(v.z * inv); o.w = f2bf(v.w * inv);
    reinterpret_cast<ushort4*>(Enb + (size_t)row * DIMS)[l] = o;
    return;
  }
  if (b < 936){
    const int id = b - 832;
    const int tp = id >> 2, ck = id & 3;
    __shared__ float T[32][260];
    const int row = t >> 3, sub = t & 7;
    const float* src = E + (size_t)(tp*NPT + ck*32 + row) * DIMS;
#pragma unroll
    for (int i = 0; i < 8; ++i){
      const int c4 = sub + 8*i;
      *(f32x4*)(&T[row][c4*4]) = *(const f32x4*)(src + c4*4);
    }
    __syncthreads();
    ushort_t* dst = EC + (size_t)(tp*4 + ck) * 8192;
#pragma unroll
    for (int i = 0; i < 4; ++i){
      const int si = t + i*256;
      const int sec = si >> 8, d = (si >> 2) & 63, s = si & 3;
      const int cb8 = (s ^ ((d >> 1) & 3)) * 8;
      union { bf16x8 v8; ushort_t u[8]; } pk;
#pragma unroll
      for (int j = 0; j < 8; ++j)
        pk.u[j] = f2bf(T[cb8 + j][sec*64 + d]);
      *(bf16x8*)(dst + (size_t)si*8) = pk.v8;
    }
    return;
  }
  if (b < 1144){
    const int id = b - 936;
    const int tp = id >> 3, kt = id & 7;
    float* dst = EA2 + (size_t)tp*32768 + kt*1024;   // chunk (sec*8+kt)*1024
    const float* src = E + (size_t)tp * NPT * DIMS;
#pragma unroll
    for (int i = 0; i < 16; ++i){
      const int e = i*256 + t;                       // 0..4095
      const int sec = e >> 10, code = (e >> 3) & 127, j = e & 7;
      dst[sec*8192 + code*8 + j] = src[(size_t)code*DIMS + sec*64 + kt*8 + j];
    }
    return;
  }
  {
    __shared__ int h[NUM_TYPES];
    if (t < NUM_TYPES) h[t] = 0;
    __syncthreads();
    const int c = b - 1144;
    atomicAdd(&h[Q[c*256 + t]], 1);
    __syncthreads();
    if (t < NUM_TYPES) bh[c*NUM_TYPES + t] = h[t];
  }
}

// ---------------- gramk: Gram upper-tri; scatter+scan on idle blocks --------
__global__ __launch_bounds__(256) void gramk(const ushort_t* __restrict__ Enb,
                                             const int* __restrict__ Q,
                                             const int* __restrict__ bh,
                                             int* __restrict__ counts,
                                             int* __restrict__ offsets,
                                             int* __restrict__ perm,
                                             float* __restrict__ part){
  const int bi = blockIdx.y, bj = blockIdx.x;
  const int t = threadIdx.x;
  if (bi > bj){
    const int lid = bi*(bi-1)/2 + bj;
    if (lid >= NHIST) return;
    __shared__ int sh_tot[NUM_TYPES], sh_off[NUM_TYPES], sh_cur[NUM_TYPES];
    if (t < NUM_TYPES){
      int s = 0;
      for (int h = 0; h < NHIST; ++h) s += bh[h*NUM_TYPES + t];
      sh_tot[t] = s;
    }
    __syncthreads();
    if (t == 0){
      int s = 0;
      for (int g = 0; g < NUM_TYPES; ++g){ sh_off[g] = s; s += sh_tot[g]; }
    }
    __syncthreads();
    if (t < NUM_TYPES){
      int run = sh_off[t];
      for (int h = 0; h < lid; ++h) run += bh[h*NUM_TYPES + t];
      sh_cur[t] = run;
      if (lid == 0){ counts[t] = sh_tot[t]; offsets[t] = sh_off[t]; }
    }
    __syncthreads();
    const int i = lid*256 + t;
    const int q = Q[i];
    const int pos = atomicAdd(&sh_cur[q], 1);
    perm[pos] = i;   // within-type order nondeterministic; per-token outputs invariant
    return;
  }
  __shared__ ushort_t As[128*64];
  __shared__ ushort_t Bs[128*64];
  __shared__ float rs[128][2];
  __shared__ float cs[128][2];
  const int w = t >> 6, l = t & 63;
  const int wr = w >> 1, wc = w & 1;
  const int lrow = l & 15;
  const int lk = (l >> 4) * 8;
  const int hi = l >> 4;

  f32x4 acc[4][4];
#pragma unroll
  for (int m = 0; m < 4; ++m)
#pragma unroll
    for (int n = 0; n < 4; ++n) acc[m][n] = (f32x4){0.f, 0.f, 0.f, 0.f};

  for (int kt = 0; kt < 4; ++kt){
    if (kt) __syncthreads();
#pragma unroll
    for (int p = 0; p < 4; ++p){
      const int cbase = p*256 + w*64;
      const int c = cbase + l;
      const int row = c >> 3;
      const int kcol = (c & 7) * 8;
      const ushort_t* gA = Enb + (size_t)(bi*128 + row) * DIMS + kt*64 + kcol;
      const ushort_t* gB = Enb + (size_t)(bj*128 + row) * DIMS + kt*64 + kcol;
      GLOAD_LDS16(gA, As + (size_t)cbase*8);
      GLOAD_LDS16(gB, Bs + (size_t)cbase*8);
    }
    __syncthreads();
#pragma unroll
    for (int kk = 0; kk < 2; ++kk){
      bf16x8 a[4], b[4];
#pragma unroll
      for (int m = 0; m < 4; ++m)
        a[m] = *reinterpret_cast<const bf16x8*>(&As[(wr*64 + m*16 + lrow)*64 + kk*32 + lk]);
#pragma unroll
      for (int n = 0; n < 4; ++n)
        b[n] = *reinterpret_cast<const bf16x8*>(&Bs[(wc*64 + n*16 + lrow)*64 + kk*32 + lk]);
#pragma unroll
      for (int m = 0; m < 4; ++m)
#pragma unroll
        for (int n = 0; n < 4; ++n)
          acc[m][n] = __builtin_amdgcn_mfma_f32_16x16x32_bf16(a[m], b[n], acc[m][n], 0, 0, 0);
    }
  }

#pragma unroll
  for (int m = 0; m < 4; ++m)
#pragma unroll
    for (int n = 0; n < 4; ++n)
#pragma unroll
      for (int j = 0; j < 4; ++j){
        const int grow = bi*128 + wr*64 + m*16 + hi*4 + j;
        const int gcol = bj*128 + wc*64 + n*16 + lrow;
        const float g = acc[m][n][j];
        acc[m][n][j] = (grow == gcol) ? 0.f : __expf(g * INV_TEMP);
      }

#pragma unroll
  for (int m = 0; m < 4; ++m)
#pragma unroll
    for (int j = 0; j < 4; ++j){
      float s = 0.f;
#pragma unroll
      for (int n = 0; n < 4; ++n) s += acc[m][n][j];
#pragma unroll
      for (int off = 1; off < 16; off <<= 1) s += __shfl_xor(s, off);
      if (lrow == 0) rs[wr*64 + m*16 + hi*4 + j][wc] = s;
    }
  if (bi != bj){
#pragma unroll
    for (int n = 0; n < 4; ++n){
      float c = 0.f;
#pragma unroll
      for (int m = 0; m < 4; ++m)
#pragma unroll
        for (int j = 0; j < 4; ++j) c += acc[m][n][j];
      c += __shfl_xor(c, 16); c += __shfl_xor(c, 32);
      if (hi == 0) cs[wc*64 + n*16 + lrow][wr] = c;
    }
  }
  __syncthreads();
  if (t < 128){
    part[(size_t)bj*K_TOTAL + bi*128 + t] = rs[t][0] + rs[t][1];
    if (bi != bj)
      part[(size_t)bi*K_TOTAL + bj*128 + t] = cs[t][0] + cs[t][1];
  }
}

// ---------------- quantg v14: LDS-free phase A (scalar A, global-reg B) -----
// 512 thr, wave w = (sec = w>>1, cg = w&1); lane = code cg*64+l.
__device__ __forceinline__ void stageC5(const ushort_t* EC, char* dst, int tp, int ck,
                                        int sec, int dh, int l){
  const char* src = (const char*)(EC + (size_t)(tp*4 + ck) * 8192) + sec*4096 + dh*2048;
  char* d = dst + sec*4096 + dh*2048;
#pragma unroll
  for (int i = 0; i < 2; ++i)
    GLOAD_LDS16(src + i*1024 + l*16, d + i*1024);
}

__global__ __launch_bounds__(512, 1) void quantg(const float* __restrict__ x,
                                                 const float* __restrict__ EA2,
                                                 const ushort_t* __restrict__ EC,
                                                 const float* __restrict__ part,
                                                 const int* __restrict__ counts,
                                                 const int* __restrict__ offsets,
                                                 const int* __restrict__ perm,
                                                 const int* __restrict__ taup,
                                                 float* __restrict__ outZ,
                                                 float* __restrict__ outMisc,
                                                 float* __restrict__ outIdx){
  const int t = threadIdx.x;
  const int tp = blockIdx.x, rb = blockIdx.y;
  // Arena 53504 B -> 3 blocks/CU (160512 <= 163840). Overlays:
  //  phase A: NO LDS. PB @0 (4 sec x 16 rows x 512B = 32768)
  //  phase B: reads PB, writes SB @49152 (16 x 272 = 4352)
  //  phase C: BC @0 (3x16K = 49152, over dead PB) | SB stays live
  __shared__ __align__(16) char arena[53504];

  // ---- fused uniform-loss block ----
  if (tp == NUM_TYPES){
    if (rb) return;
    float acc = 0.f;
    for (int i = t; i < K_TOTAL; i += 512){
      float s = 0.f;
#pragma unroll
      for (int bb = 0; bb < NUM_TYPES; ++bb) s += part[(size_t)bb*K_TOTAL + i];
      acc += logf(s) - logf(part[(size_t)(i >> 7)*K_TOTAL + i]);
    }
    acc = wave_reduce_sum(acc);
    float* red = (float*)arena;
    if ((t & 63) == 0) red[t >> 6] = acc;
    __syncthreads();
    if (t == 0){
      float s = 0.f;
#pragma unroll
      for (int i2 = 0; i2 < 8; ++i2) s += red[i2];
      outMisc[0] = 0.f; outMisc[1] = s / (float)K_TOTAL;
    }
    return;
  }

  const int cnt = counts[tp];
  if (rb * TM >= cnt) return;
  const int nt = min(TM, cnt - rb * TM);
  const int off = offsets[tp] + rb * TM;

  char* PB = arena;
  char* BC = arena;
  char* SB = arena + 49152;

  const int w = t >> 6, l = t & 63;
  const int sec = w >> 1;
  const int cg  = w & 1;
  const int tx = l & 15, ty = l >> 4;

  const int ti = *taup;
  const float tau = (ti > 0 && ti < (1 << 23)) ? (float)ti : __int_as_float(ti);
  const float inv_tau = 1.0f / tau;

  // ---- wave-uniform token ids (SGPRs) ----
  int tid16[16];
#pragma unroll
  for (int rr = 0; rr < 16; ++rr)
    tid16[rr] = (rr < nt) ? perm[off + rr] : perm[off];

  // ---- Phase A: LDS-free f32 dots. lane = code; A uniform (scalar), B reg ----
  float acc[16];
#pragma unroll
  for (int rr = 0; rr < 16; ++rr) acc[rr] = 0.f;

  const int code = cg*64 + l;
  const float* ea = EA2 + (size_t)tp*32768 + sec*8192 + code*8;
#pragma unroll
  for (int kt = 0; kt < 8; ++kt){
    const f32x4 b0 = *(const f32x4*)(ea + kt*1024);
    const f32x4 b1 = *(const f32x4*)(ea + kt*1024 + 4);
#pragma unroll
    for (int rr = 0; rr < 16; ++rr){
      const float* xr = x + (size_t)tid16[rr]*DIMS + sec*64 + kt*8;
#pragma unroll
      for (int e = 0; e < 4; ++e){
        acc[rr] = fmaf(xr[e],     b0[e], acc[rr]);
        acc[rr] = fmaf(xr[4 + e], b1[e], acc[rr]);
      }
    }
  }

  // ---- PB[sec][row][code] partials (coalesced b32, one writer/cell) ----
#pragma unroll
  for (int rr = 0; rr < 16; ++rr)
    *(float*)(PB + sec*8192 + rr*512 + code*4) = acc[rr];
  __syncthreads();                                        // bar1: PB ready

  // ---- Phase B: softmax + argmax (16 rows x 16 lanes; threads 0..255) ----
  if (t < 256){
    const int r = t >> 4, s = t & 15;
    f32x4 v0 = (f32x4){0,0,0,0}, v1 = (f32x4){0,0,0,0};
#pragma unroll
    for (int ww = 0; ww < 4; ++ww){
      v0 += *(const f32x4*)(PB + ww*8192 + r*512 + s*32);
      v1 += *(const f32x4*)(PB + ww*8192 + r*512 + s*32 + 16);
    }
    float v[8];
#pragma unroll
    for (int e = 0; e < 4; ++e){ v[e] = v0[e]*inv_tau; v[4+e] = v1[e]*inv_tau; }
    float m = v[0]; int mi = s*8;
#pragma unroll
    for (int j = 1; j < 8; ++j) if (v[j] > m){ m = v[j]; mi = s*8 + j; }
#pragma unroll
    for (int o = 1; o < 16; o <<= 1){
      const float om = __shfl_xor(m, o);
      const int   oi = __shfl_xor(mi, o);
      if (om > m || (om == m && oi < mi)){ m = om; mi = oi; }
    }
    float e8[8]; float sum = 0.f;
#pragma unroll
    for (int j = 0; j < 8; ++j){ e8[j] = __expf(v[j] - m); sum += e8[j]; }
#pragma unroll
    for (int o = 1; o < 16; o <<= 1) sum += __shfl_xor(sum, o);
    const float inv = 1.0f / sum;
    union { bf16x8 v8; ushort_t u[8]; } pk;
#pragma unroll
    for (int j = 0; j < 8; ++j) pk.u[j] = f2bf(e8[j] * inv);
    *(bf16x8*)(SB + r*272 + s*16) = pk.v8;
    if (s == 0 && r < nt)
      outIdx[perm[off + r]] = (float)(mi + tp * NPT);
  }
  __syncthreads();                                        // bar2: S ready, PB dead

  // ---- Phase C: Z = S @ E via MFMA; wave owns 32-dim half-section ----
  stageC5(EC, BC,         tp, 0, sec, cg, l);
  stageC5(EC, BC + 16384, tp, 1, sec, cg, l);
  f32x4 zacc[2];
#pragma unroll
  for (int n = 0; n < 2; ++n) zacc[n] = (f32x4){0,0,0,0};
#pragma unroll
  for (int ck = 0; ck < 4; ++ck){
    if (ck < 2) stageC5(EC, BC + ((ck+2)%3)*16384, tp, ck+2, sec, cg, l);
    if (ck < 2)      { VMWAIT(4); }
    else if (ck == 2){ VMWAIT(2); }
    else             { VMWAIT(0); }
    const char* bbuf = BC + (ck%3)*16384 + sec*4096 + cg*2048;
    const bf16x8 af = *(const bf16x8*)(SB + tx*272 + ck*64 + ty*16);
#pragma unroll
    for (int n = 0; n < 2; ++n){
      const int dsec = cg*32 + n*16 + tx;                 // dim within 64-sec
      const int slot = ty ^ ((dsec >> 1) & 3);
      const bf16x8 bf = *(const bf16x8*)(bbuf + (n*16 + tx)*64 + slot*16);
      zacc[n] = __builtin_amdgcn_mfma_f32_16x16x32_bf16(af, bf, zacc[n], 0, 0, 0);
    }
  }
#pragma unroll
  for (int n = 0; n < 2; ++n)
#pragma unroll
    for (int j = 0; j < 4; ++j){
      const int row = ty*4 + j;
      if (row < nt)
        outZ[(size_t)perm[off + row]*DIMS + sec*64 + cg*32 + n*16 + tx] = zacc[n][j];
    }
}

extern "C" void kernel_launch(void* const* d_in, const int* in_sizes, int n_in,
                              void* d_out, int out_size, void* d_ws, size_t ws_size,
                              hipStream_t stream){
  const float* x  = (const float*)d_in[0];
  const int*   Q  = (const int*)d_in[1];
  const float* E  = (const float*)d_in[2];
  const int* taup = (const int*)d_in[3];

  float* outZ    = (float*)d_out;
  float* outMisc = outZ + (size_t)N_TOK * DIMS;
  float* outIdx  = outMisc + 2;

  char* wsp = (char*)d_ws;
  ushort_t* Enb = (ushort_t*)wsp;                    // 1,703,936
  float* part   = (float*)(wsp + 1703936);           //   346,112
  float* EA2    = (float*)(wsp + 2050048);           // 3,407,872
  ushort_t* EC  = (ushort_t*)(wsp + 5457920);        // 1,703,936
  int* bh       = (int*)(wsp + 7161856);             //     3,328
  int* counts   = (int*)(wsp + 7165184);
  int* offsets  = (int*)(wsp + 7165312);
  int* perm     = (int*)(wsp + 7165440);             //    32,768

  prepk<<<1176, 256, 0, stream>>>(E, Q, Enb, EA2, EC, bh);
  gramk<<<dim3(26, 26), 256, 0, stream>>>(Enb, Q, bh, counts, offsets, perm, part);
  quantg<<<dim3(NUM_TYPES + 1, MAX_TILES), 512, 0, stream>>>(x, EA2, EC, part,
                                                             counts, offsets, perm,
                                                             taup, outZ, outMisc, outIdx);
}

// Round 15
// 47.879 us; speedup vs baseline: 2.0029x; 2.0029x over previous
//
#include <hip/hip_runtime.h>
#include <hip/hip_bf16.h>

#define NUM_TYPES 26
#define NPT 128
#define DIMS 256
#define K_TOTAL 3328
#define N_TOK 8192
#define INV_TEMP (1.0f/0.07f)
#define TM 32
#define MAX_TILES 16
#define NHIST 32

typedef unsigned short ushort_t;
typedef short bf16x8 __attribute__((ext_vector_type(8)));
typedef float f32x4 __attribute__((ext_vector_type(4)));

__device__ __forceinline__ float wave_reduce_sum(float v){
#pragma unroll
  for (int off = 32; off; off >>= 1) v += __shfl_xor(v, off);
  return v;
}

__device__ __forceinline__ unsigned short f2bf(float f){
  __hip_bfloat16 h = __float2bfloat16(f);
  return __builtin_bit_cast(unsigned short, h);
}

#define GLOAD_LDS16(g, s) \
  __builtin_amdgcn_global_load_lds((__attribute__((address_space(1))) void*)(g), \
                                   (__attribute__((address_space(3))) void*)(s), 16, 0, 0)

#define VMWAIT(N) do{ asm volatile("s_waitcnt vmcnt(" #N ")" ::: "memory"); \
                      __builtin_amdgcn_sched_barrier(0); }while(0)

// ---------------- prepk -----------------------------------------------------
// blocks 0..831    : normalize E rows -> Enb (bf16)
// blocks 832..935  : pack EC[tp][ck] (bf16, phase-C tile order, 16KB each)
// blocks 936..1143 : pack EA2[tp][sec][kt][code][8] (f32, plain; R14-verified)
// blocks 1144..1175: histogram chunks
__global__ __launch_bounds__(256) void prepk(const float* __restrict__ E,
                                             const int* __restrict__ Q,
                                             ushort_t* __restrict__ Enb,
                                             float* __restrict__ EA2,
                                             ushort_t* __restrict__ EC,
                                             int* __restrict__ bh){
  const int t = threadIdx.x;
  const int b = blockIdx.x;
  if (b < 832){
    const int w = t >> 6, l = t & 63;
    const int row = b * 4 + w;
    float4 v = reinterpret_cast<const float4*>(E + (size_t)row * DIMS)[l];
    float ss = v.x*v.x + v.y*v.y + v.z*v.z + v.w*v.w;
    ss = wave_reduce_sum(ss);
    const float inv = 1.0f / sqrtf(ss);
    ushort4 o;
    o.x = f2bf(v.x * inv); o.y = f2bf(v.y * inv);
    o.z = f2bf(v.z * inv); o.w = f2bf(v.w * inv);
    reinterpret_cast<ushort4*>(Enb + (size_t)row * DIMS)[l] = o;
    return;
  }
  if (b < 936){
    const int id = b - 832;
    const int tp = id >> 2, ck = id & 3;
    __shared__ float T[32][260];
    const int row = t >> 3, sub = t & 7;
    const float* src = E + (size_t)(tp*NPT + ck*32 + row) * DIMS;
#pragma unroll
    for (int i = 0; i < 8; ++i){
      const int c4 = sub + 8*i;
      *(f32x4*)(&T[row][c4*4]) = *(const f32x4*)(src + c4*4);
    }
    __syncthreads();
    ushort_t* dst = EC + (size_t)(tp*4 + ck) * 8192;
#pragma unroll
    for (int i = 0; i < 4; ++i){
      const int si = t + i*256;
      const int sec = si >> 8, d = (si >> 2) & 63, s = si & 3;
      const int cb8 = (s ^ ((d >> 1) & 3)) * 8;
      union { bf16x8 v8; ushort_t u[8]; } pk;
#pragma unroll
      for (int j = 0; j < 8; ++j)
        pk.u[j] = f2bf(T[cb8 + j][sec*64 + d]);
      *(bf16x8*)(dst + (size_t)si*8) = pk.v8;
    }
    return;
  }
  if (b < 1144){
    const int id = b - 936;
    const int tp = id >> 3, kt = id & 7;
    float* dst = EA2 + (size_t)tp*32768 + kt*1024;   // [tp][sec][kt][code][8]
    const float* src = E + (size_t)tp * NPT * DIMS;
#pragma unroll
    for (int i = 0; i < 16; ++i){
      const int e = i*256 + t;                       // 0..4095
      const int sec = e >> 10, code = (e >> 3) & 127, j = e & 7;
      dst[sec*8192 + code*8 + j] = src[(size_t)code*DIMS + sec*64 + kt*8 + j];
    }
    return;
  }
  {
    __shared__ int h[NUM_TYPES];
    if (t < NUM_TYPES) h[t] = 0;
    __syncthreads();
    const int c = b - 1144;
    atomicAdd(&h[Q[c*256 + t]], 1);
    __syncthreads();
    if (t < NUM_TYPES) bh[c*NUM_TYPES + t] = h[t];
  }
}

// ---------------- gramk: Gram upper-tri; scatter+scan on idle blocks --------
__global__ __launch_bounds__(256) void gramk(const ushort_t* __restrict__ Enb,
                                             const int* __restrict__ Q,
                                             const int* __restrict__ bh,
                                             int* __restrict__ counts,
                                             int* __restrict__ offsets,
                                             int* __restrict__ perm,
                                             float* __restrict__ part){
  const int bi = blockIdx.y, bj = blockIdx.x;
  const int t = threadIdx.x;
  if (bi > bj){
    const int lid = bi*(bi-1)/2 + bj;
    if (lid >= NHIST) return;
    __shared__ int sh_tot[NUM_TYPES], sh_off[NUM_TYPES], sh_cur[NUM_TYPES];
    if (t < NUM_TYPES){
      int s = 0;
      for (int h = 0; h < NHIST; ++h) s += bh[h*NUM_TYPES + t];
      sh_tot[t] = s;
    }
    __syncthreads();
    if (t == 0){
      int s = 0;
      for (int g = 0; g < NUM_TYPES; ++g){ sh_off[g] = s; s += sh_tot[g]; }
    }
    __syncthreads();
    if (t < NUM_TYPES){
      int run = sh_off[t];
      for (int h = 0; h < lid; ++h) run += bh[h*NUM_TYPES + t];
      sh_cur[t] = run;
      if (lid == 0){ counts[t] = sh_tot[t]; offsets[t] = sh_off[t]; }
    }
    __syncthreads();
    const int i = lid*256 + t;
    const int q = Q[i];
    const int pos = atomicAdd(&sh_cur[q], 1);
    perm[pos] = i;   // within-type order nondeterministic; per-token outputs invariant
    return;
  }
  __shared__ ushort_t As[128*64];
  __shared__ ushort_t Bs[128*64];
  __shared__ float rs[128][2];
  __shared__ float cs[128][2];
  const int w = t >> 6, l = t & 63;
  const int wr = w >> 1, wc = w & 1;
  const int lrow = l & 15;
  const int lk = (l >> 4) * 8;
  const int hi = l >> 4;

  f32x4 acc[4][4];
#pragma unroll
  for (int m = 0; m < 4; ++m)
#pragma unroll
    for (int n = 0; n < 4; ++n) acc[m][n] = (f32x4){0.f, 0.f, 0.f, 0.f};

  for (int kt = 0; kt < 4; ++kt){
    if (kt) __syncthreads();
#pragma unroll
    for (int p = 0; p < 4; ++p){
      const int cbase = p*256 + w*64;
      const int c = cbase + l;
      const int row = c >> 3;
      const int kcol = (c & 7) * 8;
      const ushort_t* gA = Enb + (size_t)(bi*128 + row) * DIMS + kt*64 + kcol;
      const ushort_t* gB = Enb + (size_t)(bj*128 + row) * DIMS + kt*64 + kcol;
      GLOAD_LDS16(gA, As + (size_t)cbase*8);
      GLOAD_LDS16(gB, Bs + (size_t)cbase*8);
    }
    __syncthreads();
#pragma unroll
    for (int kk = 0; kk < 2; ++kk){
      bf16x8 a[4], b[4];
#pragma unroll
      for (int m = 0; m < 4; ++m)
        a[m] = *reinterpret_cast<const bf16x8*>(&As[(wr*64 + m*16 + lrow)*64 + kk*32 + lk]);
#pragma unroll
      for (int n = 0; n < 4; ++n)
        b[n] = *reinterpret_cast<const bf16x8*>(&Bs[(wc*64 + n*16 + lrow)*64 + kk*32 + lk]);
#pragma unroll
      for (int m = 0; m < 4; ++m)
#pragma unroll
        for (int n = 0; n < 4; ++n)
          acc[m][n] = __builtin_amdgcn_mfma_f32_16x16x32_bf16(a[m], b[n], acc[m][n], 0, 0, 0);
    }
  }

#pragma unroll
  for (int m = 0; m < 4; ++m)
#pragma unroll
    for (int n = 0; n < 4; ++n)
#pragma unroll
      for (int j = 0; j < 4; ++j){
        const int grow = bi*128 + wr*64 + m*16 + hi*4 + j;
        const int gcol = bj*128 + wc*64 + n*16 + lrow;
        const float g = acc[m][n][j];
        acc[m][n][j] = (grow == gcol) ? 0.f : __expf(g * INV_TEMP);
      }

#pragma unroll
  for (int m = 0; m < 4; ++m)
#pragma unroll
    for (int j = 0; j < 4; ++j){
      float s = 0.f;
#pragma unroll
      for (int n = 0; n < 4; ++n) s += acc[m][n][j];
#pragma unroll
      for (int off = 1; off < 16; off <<= 1) s += __shfl_xor(s, off);
      if (lrow == 0) rs[wr*64 + m*16 + hi*4 + j][wc] = s;
    }
  if (bi != bj){
#pragma unroll
    for (int n = 0; n < 4; ++n){
      float c = 0.f;
#pragma unroll
      for (int m = 0; m < 4; ++m)
#pragma unroll
        for (int j = 0; j < 4; ++j) c += acc[m][n][j];
      c += __shfl_xor(c, 16); c += __shfl_xor(c, 32);
      if (hi == 0) cs[wc*64 + n*16 + lrow][wr] = c;
    }
  }
  __syncthreads();
  if (t < 128){
    part[(size_t)bj*K_TOTAL + bi*128 + t] = rs[t][0] + rs[t][1];
    if (bi != bj)
      part[(size_t)bi*K_TOTAL + bj*128 + t] = cs[t][0] + cs[t][1];
  }
}

// ---------------- quantg v15: LDS-A (staged X) + global-streamed B ----------
// 512 thr, wave w = (sec = w>>1, cg = w&1). Phase A B-operand from EA2 (VMEM),
// X from LDS (R13 path). Phases B/C verbatim R13.
__device__ __forceinline__ void stageC5(const ushort_t* EC, char* dst, int tp, int ck,
                                        int sec, int dh, int l){
  const char* src = (const char*)(EC + (size_t)(tp*4 + ck) * 8192) + sec*4096 + dh*2048;
  char* d = dst + sec*4096 + dh*2048;
#pragma unroll
  for (int i = 0; i < 2; ++i)
    GLOAD_LDS16(src + i*1024 + l*16, d + i*1024);
}

__global__ __launch_bounds__(512, 1) void quantg(const float* __restrict__ x,
                                                 const float* __restrict__ EA2,
                                                 const ushort_t* __restrict__ EC,
                                                 const float* __restrict__ part,
                                                 const int* __restrict__ counts,
                                                 const int* __restrict__ offsets,
                                                 const int* __restrict__ perm,
                                                 const int* __restrict__ taup,
                                                 float* __restrict__ outZ,
                                                 float* __restrict__ outMisc,
                                                 float* __restrict__ outIdx){
  const int t = threadIdx.x;
  const int rb = blockIdx.x, tp = blockIdx.y;   // rb-fastest: same-tp blocks adjacent
  // Arena 72192 B -> 2 blocks/CU. Overlays (phase-disjoint, barrier-separated):
  //  phase A: XA @0 (32K) ; B streamed from global (no BA)
  //  partials: PB @0 (4 sec x 32 rows x 528 = 67584, over dead XA)
  //  phase B: reads PB, writes SB @67840 (8704)
  //  phase C: BC @0 (3x16K = 49152, over dead PB) | SB stays live
  __shared__ __align__(16) char arena[72192];

  // ---- fused uniform-loss block ----
  if (tp == NUM_TYPES){
    if (rb) return;
    float acc = 0.f;
    for (int i = t; i < K_TOTAL; i += 512){
      float s = 0.f;
#pragma unroll
      for (int bb = 0; bb < NUM_TYPES; ++bb) s += part[(size_t)bb*K_TOTAL + i];
      acc += logf(s) - logf(part[(size_t)(i >> 7)*K_TOTAL + i]);
    }
    acc = wave_reduce_sum(acc);
    float* red = (float*)arena;
    if ((t & 63) == 0) red[t >> 6] = acc;
    __syncthreads();
    if (t == 0){
      float s = 0.f;
#pragma unroll
      for (int i2 = 0; i2 < 8; ++i2) s += red[i2];
      outMisc[0] = 0.f; outMisc[1] = s / (float)K_TOTAL;
    }
    return;
  }

  const int cnt = counts[tp];
  if (rb * TM >= cnt) return;
  const int nt = min(TM, cnt - rb * TM);
  const int off = offsets[tp] + rb * TM;

  char* XA = arena;
  char* PB = arena;
  char* BC = arena;
  char* SB = arena + 67840;

  const int w = t >> 6, l = t & 63;
  const int sec = w >> 1;        // 64-dim section
  const int cg  = w & 1;         // code-half (A) / dim-half (C)
  const int tx = l & 15, ty = l >> 4;

  const int ti = *taup;
  const float tau = (ti > 0 && ti < (1 << 23)) ? (float)ti : __int_as_float(ti);
  const float inv_tau = 1.0f / tau;

  // ---- stage X (32 rows, 4/wave, source-swizzled) ----
#pragma unroll
  for (int i = 0; i < 4; ++i){
    const int row = w*4 + i;                              // wave-uniform
    const int tid = (row < nt) ? perm[off + row] : perm[off];
    const int sc = (l & 56) | ((l & 7) ^ (row & 7));
    GLOAD_LDS16(x + (size_t)tid*DIMS + sc*4, XA + row*1024);
  }
  __syncthreads();                                        // bar1: X staged

  // ---- Phase A: f32 dots; 8 rows x 4 codes; B streamed from EA2 (VMEM) ----
  float acc[8][4];
#pragma unroll
  for (int rr = 0; rr < 8; ++rr)
#pragma unroll
    for (int cc = 0; cc < 4; ++cc) acc[rr][cc] = 0.f;

  const float* ea = EA2 + (size_t)tp*32768 + sec*8192;    // [kt][code][8]
#pragma unroll
  for (int kt = 0; kt < 8; ++kt){
    f32x4 b0[4], b1[4];
#pragma unroll
    for (int cc = 0; cc < 4; ++cc){
      const float* p = ea + kt*1024 + (size_t)(cg*64 + tx + 16*cc)*8;
      b0[cc] = *(const f32x4*)(p);
      b1[cc] = *(const f32x4*)(p + 4);
    }
#pragma unroll
    for (int q = 0; q < 2; ++q){
      f32x4 a[8];
#pragma unroll
      for (int rr = 0; rr < 8; ++rr){
        const int row = rr*4 + ty;
        const int c = (sec*16 + kt*2 + q) ^ (row & 7);
        a[rr] = *(const f32x4*)(XA + row*1024 + c*16);
      }
#pragma unroll
      for (int rr = 0; rr < 8; ++rr)
#pragma unroll
        for (int cc = 0; cc < 4; ++cc)
#pragma unroll
          for (int e = 0; e < 4; ++e)
            acc[rr][cc] = fmaf(a[rr][e], (q ? b1 : b0)[cc][e], acc[rr][cc]);
    }
  }
  __syncthreads();                                        // bar2: XA dead

  // ---- per-wave partials PB[sec][row][code] (one writer per cell) ----
#pragma unroll
  for (int rr = 0; rr < 8; ++rr){
    const int row = rr*4 + ty;
#pragma unroll
    for (int cc = 0; cc < 4; ++cc)
      *(float*)(PB + sec*16896 + row*528 + (cg*64 + tx + 16*cc)*4) = acc[rr][cc];
  }
  __syncthreads();                                        // bar3: PB ready

  // ---- Phase B: softmax + argmax (32 rows x 16 lanes), emit bf16 S ----
  {
    const int r = t >> 4, s = t & 15;
    f32x4 v0 = (f32x4){0,0,0,0}, v1 = (f32x4){0,0,0,0};
#pragma unroll
    for (int ww = 0; ww < 4; ++ww){
      v0 += *(const f32x4*)(PB + ww*16896 + r*528 + s*32);
      v1 += *(const f32x4*)(PB + ww*16896 + r*528 + s*32 + 16);
    }
    float v[8];
#pragma unroll
    for (int e = 0; e < 4; ++e){ v[e] = v0[e]*inv_tau; v[4+e] = v1[e]*inv_tau; }
    float m = v[0]; int mi = s*8;
#pragma unroll
    for (int j = 1; j < 8; ++j) if (v[j] > m){ m = v[j]; mi = s*8 + j; }
#pragma unroll
    for (int o = 1; o < 16; o <<= 1){
      const float om = __shfl_xor(m, o);
      const int   oi = __shfl_xor(mi, o);
      if (om > m || (om == m && oi < mi)){ m = om; mi = oi; }
    }
    float e8[8]; float sum = 0.f;
#pragma unroll
    for (int j = 0; j < 8; ++j){ e8[j] = __expf(v[j] - m); sum += e8[j]; }
#pragma unroll
    for (int o = 1; o < 16; o <<= 1) sum += __shfl_xor(sum, o);
    const float inv = 1.0f / sum;
    union { bf16x8 v8; ushort_t u[8]; } pk;
#pragma unroll
    for (int j = 0; j < 8; ++j) pk.u[j] = f2bf(e8[j] * inv);
    *(bf16x8*)(SB + r*272 + s*16) = pk.v8;
    if (s == 0 && r < nt)
      outIdx[perm[off + r]] = (float)(mi + tp * NPT);
  }
  __syncthreads();                                        // bar4: S ready, PB dead

  // ---- Phase C: Z = S @ E via MFMA; wave owns 32-dim half-section ----
  stageC5(EC, BC,         tp, 0, sec, cg, l);
  stageC5(EC, BC + 16384, tp, 1, sec, cg, l);
  f32x4 zacc[2][2];
#pragma unroll
  for (int g = 0; g < 2; ++g)
#pragma unroll
    for (int n = 0; n < 2; ++n) zacc[g][n] = (f32x4){0,0,0,0};
#pragma unroll
  for (int ck = 0; ck < 4; ++ck){
    if (ck < 2) stageC5(EC, BC + ((ck+2)%3)*16384, tp, ck+2, sec, cg, l);
    if (ck < 2)      { VMWAIT(4); }
    else if (ck == 2){ VMWAIT(2); }
    else             { VMWAIT(0); }
    const char* bbuf = BC + (ck%3)*16384 + sec*4096 + cg*2048;
#pragma unroll
    for (int g = 0; g < 2; ++g){
      const bf16x8 af = *(const bf16x8*)(SB + (g*16 + tx)*272 + ck*64 + ty*16);
#pragma unroll
      for (int n = 0; n < 2; ++n){
        const int dsec = cg*32 + n*16 + tx;               // dim within 64-sec
        const int slot = ty ^ ((dsec >> 1) & 3);
        const bf16x8 bf = *(const bf16x8*)(bbuf + (n*16 + tx)*64 + slot*16);
        zacc[g][n] = __builtin_amdgcn_mfma_f32_16x16x32_bf16(af, bf, zacc[g][n], 0, 0, 0);
      }
    }
  }
#pragma unroll
  for (int g = 0; g < 2; ++g)
#pragma unroll
    for (int n = 0; n < 2; ++n)
#pragma unroll
      for (int j = 0; j < 4; ++j){
        const int row = g*16 + ty*4 + j;
        if (row < nt)
          outZ[(size_t)perm[off + row]*DIMS + sec*64 + cg*32 + n*16 + tx] = zacc[g][n][j];
      }
}

extern "C" void kernel_launch(void* const* d_in, const int* in_sizes, int n_in,
                              void* d_out, int out_size, void* d_ws, size_t ws_size,
                              hipStream_t stream){
  const float* x  = (const float*)d_in[0];
  const int*   Q  = (const int*)d_in[1];
  const float* E  = (const float*)d_in[2];
  const int* taup = (const int*)d_in[3];

  float* outZ    = (float*)d_out;
  float* outMisc = outZ + (size_t)N_TOK * DIMS;
  float* outIdx  = outMisc + 2;

  char* wsp = (char*)d_ws;
  ushort_t* Enb = (ushort_t*)wsp;                    // 1,703,936
  float* part   = (float*)(wsp + 1703936);           //   346,112
  float* EA2    = (float*)(wsp + 2050048);           // 3,407,872
  ushort_t* EC  = (ushort_t*)(wsp + 5457920);        // 1,703,936
  int* bh       = (int*)(wsp + 7161856);             //     3,328
  int* counts   = (int*)(wsp + 7165184);
  int* offsets  = (int*)(wsp + 7165312);
  int* perm     = (int*)(wsp + 7165440);             //    32,768

  prepk<<<1176, 256, 0, stream>>>(E, Q, Enb, EA2, EC, bh);
  gramk<<<dim3(26, 26), 256, 0, stream>>>(Enb, Q, bh, counts, offsets, perm, part);
  quantg<<<dim3(MAX_TILES, NUM_TYPES + 1), 512, 0, stream>>>(x, EA2, EC, part,
                                                             counts, offsets, perm,
                                                             taup, outZ, outMisc, outIdx);
}

// Round 16
// 45.867 us; speedup vs baseline: 2.0908x; 1.0439x over previous
//
#include <hip/hip_runtime.h>
#include <hip/hip_bf16.h>

#define NUM_TYPES 26
#define NPT 128
#define DIMS 256
#define K_TOTAL 3328
#define N_TOK 8192
#define INV_TEMP (1.0f/0.07f)
#define TM 16
#define MAX_TILES 32
#define NHIST 32

typedef unsigned short ushort_t;
typedef short bf16x8 __attribute__((ext_vector_type(8)));
typedef float f32x4 __attribute__((ext_vector_type(4)));

__device__ __forceinline__ float wave_reduce_sum(float v){
#pragma unroll
  for (int off = 32; off; off >>= 1) v += __shfl_xor(v, off);
  return v;
}

__device__ __forceinline__ unsigned short f2bf(float f){
  __hip_bfloat16 h = __float2bfloat16(f);
  return __builtin_bit_cast(unsigned short, h);
}

#define GLOAD_LDS16(g, s) \
  __builtin_amdgcn_global_load_lds((__attribute__((address_space(1))) void*)(g), \
                                   (__attribute__((address_space(3))) void*)(s), 16, 0, 0)

#define VMWAIT(N) do{ asm volatile("s_waitcnt vmcnt(" #N ")" ::: "memory"); \
                      __builtin_amdgcn_sched_barrier(0); }while(0)

// ---------------- prepk (R15 form, byte-identical) --------------------------
__global__ __launch_bounds__(256) void prepk(const float* __restrict__ E,
                                             const int* __restrict__ Q,
                                             ushort_t* __restrict__ Enb,
                                             float* __restrict__ EA2,
                                             ushort_t* __restrict__ EC,
                                             int* __restrict__ bh){
  const int t = threadIdx.x;
  const int b = blockIdx.x;
  if (b < 832){
    const int w = t >> 6, l = t & 63;
    const int row = b * 4 + w;
    float4 v = reinterpret_cast<const float4*>(E + (size_t)row * DIMS)[l];
    float ss = v.x*v.x + v.y*v.y + v.z*v.z + v.w*v.w;
    ss = wave_reduce_sum(ss);
    const float inv = 1.0f / sqrtf(ss);
    ushort4 o;
    o.x = f2bf(v.x * inv); o.y = f2bf(v.y * inv);
    o.z = f2bf(v.z * inv); o.w = f2bf(v.w * inv);
    reinterpret_cast<ushort4*>(Enb + (size_t)row * DIMS)[l] = o;
    return;
  }
  if (b < 936){
    const int id = b - 832;
    const int tp = id >> 2, ck = id & 3;
    __shared__ float T[32][260];
    const int row = t >> 3, sub = t & 7;
    const float* src = E + (size_t)(tp*NPT + ck*32 + row) * DIMS;
#pragma unroll
    for (int i = 0; i < 8; ++i){
      const int c4 = sub + 8*i;
      *(f32x4*)(&T[row][c4*4]) = *(const f32x4*)(src + c4*4);
    }
    __syncthreads();
    ushort_t* dst = EC + (size_t)(tp*4 + ck) * 8192;
#pragma unroll
    for (int i = 0; i < 4; ++i){
      const int si = t + i*256;
      const int sec = si >> 8, d = (si >> 2) & 63, s = si & 3;
      const int cb8 = (s ^ ((d >> 1) & 3)) * 8;
      union { bf16x8 v8; ushort_t u[8]; } pk;
#pragma unroll
      for (int j = 0; j < 8; ++j)
        pk.u[j] = f2bf(T[cb8 + j][sec*64 + d]);
      *(bf16x8*)(dst + (size_t)si*8) = pk.v8;
    }
    return;
  }
  if (b < 1144){
    const int id = b - 936;
    const int tp = id >> 3, kt = id & 7;
    float* dst = EA2 + (size_t)tp*32768 + kt*1024;   // [tp][sec][kt][code][8]
    const float* src = E + (size_t)tp * NPT * DIMS;
#pragma unroll
    for (int i = 0; i < 16; ++i){
      const int e = i*256 + t;
      const int sec = e >> 10, code = (e >> 3) & 127, j = e & 7;
      dst[sec*8192 + code*8 + j] = src[(size_t)code*DIMS + sec*64 + kt*8 + j];
    }
    return;
  }
  {
    __shared__ int h[NUM_TYPES];
    if (t < NUM_TYPES) h[t] = 0;
    __syncthreads();
    const int c = b - 1144;
    atomicAdd(&h[Q[c*256 + t]], 1);
    __syncthreads();
    if (t < NUM_TYPES) bh[c*NUM_TYPES + t] = h[t];
  }
}

// ---------------- gramk (R15 form, byte-identical) --------------------------
__global__ __launch_bounds__(256) void gramk(const ushort_t* __restrict__ Enb,
                                             const int* __restrict__ Q,
                                             const int* __restrict__ bh,
                                             int* __restrict__ counts,
                                             int* __restrict__ offsets,
                                             int* __restrict__ perm,
                                             float* __restrict__ part){
  const int bi = blockIdx.y, bj = blockIdx.x;
  const int t = threadIdx.x;
  if (bi > bj){
    const int lid = bi*(bi-1)/2 + bj;
    if (lid >= NHIST) return;
    __shared__ int sh_tot[NUM_TYPES], sh_off[NUM_TYPES], sh_cur[NUM_TYPES];
    if (t < NUM_TYPES){
      int s = 0;
      for (int h = 0; h < NHIST; ++h) s += bh[h*NUM_TYPES + t];
      sh_tot[t] = s;
    }
    __syncthreads();
    if (t == 0){
      int s = 0;
      for (int g = 0; g < NUM_TYPES; ++g){ sh_off[g] = s; s += sh_tot[g]; }
    }
    __syncthreads();
    if (t < NUM_TYPES){
      int run = sh_off[t];
      for (int h = 0; h < lid; ++h) run += bh[h*NUM_TYPES + t];
      sh_cur[t] = run;
      if (lid == 0){ counts[t] = sh_tot[t]; offsets[t] = sh_off[t]; }
    }
    __syncthreads();
    const int i = lid*256 + t;
    const int q = Q[i];
    const int pos = atomicAdd(&sh_cur[q], 1);
    perm[pos] = i;   // within-type order nondeterministic; per-token outputs invariant
    return;
  }
  __shared__ ushort_t As[128*64];
  __shared__ ushort_t Bs[128*64];
  __shared__ float rs[128][2];
  __shared__ float cs[128][2];
  const int w = t >> 6, l = t & 63;
  const int wr = w >> 1, wc = w & 1;
  const int lrow = l & 15;
  const int lk = (l >> 4) * 8;
  const int hi = l >> 4;

  f32x4 acc[4][4];
#pragma unroll
  for (int m = 0; m < 4; ++m)
#pragma unroll
    for (int n = 0; n < 4; ++n) acc[m][n] = (f32x4){0.f, 0.f, 0.f, 0.f};

  for (int kt = 0; kt < 4; ++kt){
    if (kt) __syncthreads();
#pragma unroll
    for (int p = 0; p < 4; ++p){
      const int cbase = p*256 + w*64;
      const int c = cbase + l;
      const int row = c >> 3;
      const int kcol = (c & 7) * 8;
      const ushort_t* gA = Enb + (size_t)(bi*128 + row) * DIMS + kt*64 + kcol;
      const ushort_t* gB = Enb + (size_t)(bj*128 + row) * DIMS + kt*64 + kcol;
      GLOAD_LDS16(gA, As + (size_t)cbase*8);
      GLOAD_LDS16(gB, Bs + (size_t)cbase*8);
    }
    __syncthreads();
#pragma unroll
    for (int kk = 0; kk < 2; ++kk){
      bf16x8 a[4], b[4];
#pragma unroll
      for (int m = 0; m < 4; ++m)
        a[m] = *reinterpret_cast<const bf16x8*>(&As[(wr*64 + m*16 + lrow)*64 + kk*32 + lk]);
#pragma unroll
      for (int n = 0; n < 4; ++n)
        b[n] = *reinterpret_cast<const bf16x8*>(&Bs[(wc*64 + n*16 + lrow)*64 + kk*32 + lk]);
#pragma unroll
      for (int m = 0; m < 4; ++m)
#pragma unroll
        for (int n = 0; n < 4; ++n)
          acc[m][n] = __builtin_amdgcn_mfma_f32_16x16x32_bf16(a[m], b[n], acc[m][n], 0, 0, 0);
    }
  }

#pragma unroll
  for (int m = 0; m < 4; ++m)
#pragma unroll
    for (int n = 0; n < 4; ++n)
#pragma unroll
      for (int j = 0; j < 4; ++j){
        const int grow = bi*128 + wr*64 + m*16 + hi*4 + j;
        const int gcol = bj*128 + wc*64 + n*16 + lrow;
        const float g = acc[m][n][j];
        acc[m][n][j] = (grow == gcol) ? 0.f : __expf(g * INV_TEMP);
      }

#pragma unroll
  for (int m = 0; m < 4; ++m)
#pragma unroll
    for (int j = 0; j < 4; ++j){
      float s = 0.f;
#pragma unroll
      for (int n = 0; n < 4; ++n) s += acc[m][n][j];
#pragma unroll
      for (int off = 1; off < 16; off <<= 1) s += __shfl_xor(s, off);
      if (lrow == 0) rs[wr*64 + m*16 + hi*4 + j][wc] = s;
    }
  if (bi != bj){
#pragma unroll
    for (int n = 0; n < 4; ++n){
      float c = 0.f;
#pragma unroll
      for (int m = 0; m < 4; ++m)
#pragma unroll
        for (int j = 0; j < 4; ++j) c += acc[m][n][j];
      c += __shfl_xor(c, 16); c += __shfl_xor(c, 32);
      if (hi == 0) cs[wc*64 + n*16 + lrow][wr] = c;
    }
  }
  __syncthreads();
  if (t < 128){
    part[(size_t)bj*K_TOTAL + bi*128 + t] = rs[t][0] + rs[t][1];
    if (bi != bj)
      part[(size_t)bi*K_TOTAL + bj*128 + t] = cs[t][0] + cs[t][1];
  }
}

// ---------------- quantg v16: TM=16, 256 thr, 37KB arena, 4 blocks/CU -------
// wave w = (h = w>>1 dim-half, cg = w&1 code-half); phases B/C = R9 forms.
__device__ __forceinline__ void stageC3(const ushort_t* EC, char* dst, int tp, int ck,
                                        int w, int l){
  const char* src = (const char*)(EC + (size_t)(tp*4 + ck) * 8192) + w*4096;
  char* d = dst + w*4096;
#pragma unroll
  for (int i = 0; i < 4; ++i)
    GLOAD_LDS16(src + i*1024 + l*16, d + i*1024);
}

__global__ __launch_bounds__(256, 4) void quantg(const float* __restrict__ x,
                                                 const float* __restrict__ EA2,
                                                 const ushort_t* __restrict__ EC,
                                                 const float* __restrict__ part,
                                                 const int* __restrict__ counts,
                                                 const int* __restrict__ offsets,
                                                 const int* __restrict__ perm,
                                                 const int* __restrict__ taup,
                                                 float* __restrict__ outZ,
                                                 float* __restrict__ outMisc,
                                                 float* __restrict__ outIdx){
  const int t = threadIdx.x;
  const int tp = blockIdx.x, rb = blockIdx.y;
  // Arena 37120 B -> 4 blocks/CU (148480 <= 163840). Overlays:
  //  phase A: XA @0 (16K); B streamed from EA2 (no BA)
  //  partials: PB @0 (2 h x 16 rows x 528 = 16896, over dead XA)
  //  phase B: reads PB, writes SB @32768 (4352)
  //  phase C: BC @0 (2x16K = 32768, over dead PB) | SB live @32768
  __shared__ __align__(16) char arena[37120];

  // ---- fused uniform-loss block ----
  if (tp == NUM_TYPES){
    if (rb) return;
    float acc = 0.f;
    for (int i = t; i < K_TOTAL; i += 256){
      float s = 0.f;
#pragma unroll
      for (int bb = 0; bb < NUM_TYPES; ++bb) s += part[(size_t)bb*K_TOTAL + i];
      acc += logf(s) - logf(part[(size_t)(i >> 7)*K_TOTAL + i]);
    }
    acc = wave_reduce_sum(acc);
    float* red = (float*)arena;
    if ((t & 63) == 0) red[t >> 6] = acc;
    __syncthreads();
    if (t == 0){ outMisc[0] = 0.f; outMisc[1] = (red[0]+red[1]+red[2]+red[3]) / (float)K_TOTAL; }
    return;
  }

  const int cnt = counts[tp];
  if (rb * TM >= cnt) return;
  const int nt = min(TM, cnt - rb * TM);
  const int off = offsets[tp] + rb * TM;

  char* XA = arena;
  char* PB = arena;
  char* BC = arena;
  char* SB = arena + 32768;

  const int w = t >> 6, l = t & 63;
  const int h  = w >> 1;         // dim-half (128 dims)
  const int cg = w & 1;          // code-half (64 codes)
  const int tx = l & 15, ty = l >> 4;

  const int ti = *taup;
  const float tau = (ti > 0 && ti < (1 << 23)) ? (float)ti : __int_as_float(ti);
  const float inv_tau = 1.0f / tau;

  // ---- stage X (16 rows, 4/wave, source-swizzled; R9 verbatim) ----
#pragma unroll
  for (int i = 0; i < 4; ++i){
    const int row = w*4 + i;                              // wave-uniform
    const int tid = (row < nt) ? perm[off + row] : perm[off];
    const int sc = (l & 56) | ((l & 7) ^ (row & 7));
    GLOAD_LDS16(x + (size_t)tid*DIMS + sc*4, XA + row*1024);
  }
  __syncthreads();                                        // bar1: X staged

  // ---- Phase A: f32 dots; 4 rows x 4 codes; B streamed from EA2 ----
  float acc[4][4];
#pragma unroll
  for (int rr = 0; rr < 4; ++rr)
#pragma unroll
    for (int cc = 0; cc < 4; ++cc) acc[rr][cc] = 0.f;

  const float* ea = EA2 + (size_t)tp*32768 + h*16384;     // [secH][kt][code][8]
#pragma unroll
  for (int kk = 0; kk < 16; ++kk){
    f32x4 b0[4], b1[4];
#pragma unroll
    for (int cc = 0; cc < 4; ++cc){
      const float* p = ea + (kk >> 3)*8192 + (kk & 7)*1024 + (size_t)(cg*64 + tx + 16*cc)*8;
      b0[cc] = *(const f32x4*)(p);
      b1[cc] = *(const f32x4*)(p + 4);
    }
#pragma unroll
    for (int q = 0; q < 2; ++q){
      f32x4 a[4];
#pragma unroll
      for (int rr = 0; rr < 4; ++rr){
        const int row = rr*4 + ty;
        const int c = (h*32 + kk*2 + q) ^ (row & 7);
        a[rr] = *(const f32x4*)(XA + row*1024 + c*16);
      }
#pragma unroll
      for (int rr = 0; rr < 4; ++rr)
#pragma unroll
        for (int cc = 0; cc < 4; ++cc)
#pragma unroll
          for (int e = 0; e < 4; ++e)
            acc[rr][cc] = fmaf(a[rr][e], (q ? b1 : b0)[cc][e], acc[rr][cc]);
    }
  }
  __syncthreads();                                        // bar2: XA dead

  // ---- per-wave partials PB[h][row][code] (one writer per cell) ----
#pragma unroll
  for (int rr = 0; rr < 4; ++rr){
    const int row = rr*4 + ty;
#pragma unroll
    for (int cc = 0; cc < 4; ++cc)
      *(float*)(PB + h*8448 + row*528 + (cg*64 + tx + 16*cc)*4) = acc[rr][cc];
  }
  __syncthreads();                                        // bar3: PB ready

  // ---- Phase B: softmax + argmax (16 rows x 16 lanes; R9 form) ----
  {
    const int r = t >> 4, s = t & 15;
    f32x4 v0 = (f32x4){0,0,0,0}, v1 = (f32x4){0,0,0,0};
#pragma unroll
    for (int ww = 0; ww < 2; ++ww){
      v0 += *(const f32x4*)(PB + ww*8448 + r*528 + s*32);
      v1 += *(const f32x4*)(PB + ww*8448 + r*528 + s*32 + 16);
    }
    float v[8];
#pragma unroll
    for (int e = 0; e < 4; ++e){ v[e] = v0[e]*inv_tau; v[4+e] = v1[e]*inv_tau; }
    float m = v[0]; int mi = s*8;
#pragma unroll
    for (int j = 1; j < 8; ++j) if (v[j] > m){ m = v[j]; mi = s*8 + j; }
#pragma unroll
    for (int o = 1; o < 16; o <<= 1){
      const float om = __shfl_xor(m, o);
      const int   oi = __shfl_xor(mi, o);
      if (om > m || (om == m && oi < mi)){ m = om; mi = oi; }
    }
    float e8[8]; float sum = 0.f;
#pragma unroll
    for (int j = 0; j < 8; ++j){ e8[j] = __expf(v[j] - m); sum += e8[j]; }
#pragma unroll
    for (int o = 1; o < 16; o <<= 1) sum += __shfl_xor(sum, o);
    const float inv = 1.0f / sum;
    union { bf16x8 v8; ushort_t u[8]; } pk;
#pragma unroll
    for (int j = 0; j < 8; ++j) pk.u[j] = f2bf(e8[j] * inv);
    *(bf16x8*)(SB + r*272 + s*16) = pk.v8;
    if (s == 0 && r < nt)
      outIdx[perm[off + r]] = (float)(mi + tp * NPT);
  }
  __syncthreads();                                        // bar4: S ready, PB dead

  // ---- Phase C: Z = S @ E via MFMA; R9 form, double-buffered ----
  stageC3(EC, BC, tp, 0, w, l);
  f32x4 zacc[4];
#pragma unroll
  for (int n = 0; n < 4; ++n) zacc[n] = (f32x4){0,0,0,0};
#pragma unroll
  for (int ck = 0; ck < 4; ++ck){
    if (ck < 3) stageC3(EC, BC + ((ck+1)&1)*16384, tp, ck+1, w, l);
    if (ck < 3)      { VMWAIT(4); }
    else             { VMWAIT(0); }
    const bf16x8 af = *(const bf16x8*)(SB + tx*272 + ck*64 + ty*16);
    const char* bbuf = BC + (ck&1)*16384 + w*4096;
#pragma unroll
    for (int n = 0; n < 4; ++n){
      const int d = n*16 + tx;
      const int slot = ty ^ ((d >> 1) & 3);
      const bf16x8 bf = *(const bf16x8*)(bbuf + d*64 + slot*16);
      zacc[n] = __builtin_amdgcn_mfma_f32_16x16x32_bf16(af, bf, zacc[n], 0, 0, 0);
    }
  }
#pragma unroll
  for (int n = 0; n < 4; ++n)
#pragma unroll
    for (int j = 0; j < 4; ++j){
      const int row = ty*4 + j;
      if (row < nt)
        outZ[(size_t)perm[off + row]*DIMS + w*64 + n*16 + tx] = zacc[n][j];
    }
}

extern "C" void kernel_launch(void* const* d_in, const int* in_sizes, int n_in,
                              void* d_out, int out_size, void* d_ws, size_t ws_size,
                              hipStream_t stream){
  const float* x  = (const float*)d_in[0];
  const int*   Q  = (const int*)d_in[1];
  const float* E  = (const float*)d_in[2];
  const int* taup = (const int*)d_in[3];

  float* outZ    = (float*)d_out;
  float* outMisc = outZ + (size_t)N_TOK * DIMS;
  float* outIdx  = outMisc + 2;

  char* wsp = (char*)d_ws;
  ushort_t* Enb = (ushort_t*)wsp;                    // 1,703,936
  float* part   = (float*)(wsp + 1703936);           //   346,112
  float* EA2    = (float*)(wsp + 2050048);           // 3,407,872
  ushort_t* EC  = (ushort_t*)(wsp + 5457920);        // 1,703,936
  int* bh       = (int*)(wsp + 7161856);             //     3,328
  int* counts   = (int*)(wsp + 7165184);
  int* offsets  = (int*)(wsp + 7165312);
  int* perm     = (int*)(wsp + 7165440);             //    32,768

  prepk<<<1176, 256, 0, stream>>>(E, Q, Enb, EA2, EC, bh);
  gramk<<<dim3(26, 26), 256, 0, stream>>>(Enb, Q, bh, counts, offsets, perm, part);
  quantg<<<dim3(NUM_TYPES + 1, MAX_TILES), 256, 0, stream>>>(x, EA2, EC, part,
                                                             counts, offsets, perm,
                                                             taup, outZ, outMisc, outIdx);
}